// Round 5
// baseline (468.670 us; speedup 1.0000x reference)
//
#include <hip/hip_runtime.h>

namespace {
constexpr int NN = 100000;   // nodes
constexpr int NE = 1600000;  // edges
constexpr int NF = 128;      // input feats
constexpr int NC = 40;       // classes (propagated dim after algebraic reorder)
constexpr int NB = (NN + 255) / 256;  // node blocks = 391
constexpr int EB = (NE + 255) / 256;  // edge blocks = 6250
constexpr float FIX = 1048576.0f;     // 2^20 fixed-point scale for deg
}

// Fused kernel: blocks [0,NB) do H0 = x@W (VALU-heavy), blocks [NB,NB+EB) do
// the degree/count histogram (atomic-latency-bound). Disjoint inputs; the two
// populations co-schedule across CUs so xw hides inside degcnt's latency.
__global__ __launch_bounds__(256) void k_build(const int* __restrict__ col,
                                               const float* __restrict__ w,
                                               const float* __restrict__ x,
                                               const float* __restrict__ W,
                                               unsigned long long* __restrict__ dc,
                                               unsigned short* __restrict__ rank,
                                               float* __restrict__ h0) {
    if (blockIdx.x < (unsigned)NB) {
        // ---- xw path: thread per node, 40 accumulators, no LDS ----
        int n = blockIdx.x * 256 + threadIdx.x;
        if (n >= NN) return;
        const float4* xr = (const float4*)(x + (size_t)n * NF);  // 32 float4
        const float4* W4 = (const float4*)W;                     // row k = 10 float4
        float acc[NC];
#pragma unroll
        for (int j = 0; j < NC; ++j) acc[j] = 0.f;
        for (int k4 = 0; k4 < NF / 4; ++k4) {
            float4 xv = xr[k4];
#pragma unroll
            for (int kk = 0; kk < 4; ++kk) {
                float xk = (kk == 0) ? xv.x : (kk == 1) ? xv.y : (kk == 2) ? xv.z : xv.w;
                int k = k4 * 4 + kk;
#pragma unroll
                for (int j4 = 0; j4 < 10; ++j4) {
                    float4 wv = W4[k * 10 + j4];   // block-uniform address
                    acc[j4 * 4 + 0] += xk * wv.x;
                    acc[j4 * 4 + 1] += xk * wv.y;
                    acc[j4 * 4 + 2] += xk * wv.z;
                    acc[j4 * 4 + 3] += xk * wv.w;
                }
            }
        }
        float4* o = (float4*)(h0 + (size_t)n * NC);
#pragma unroll
        for (int j4 = 0; j4 < 10; ++j4) {
            float4 v = {acc[j4 * 4 + 0], acc[j4 * 4 + 1], acc[j4 * 4 + 2], acc[j4 * 4 + 3]};
            o[j4] = v;
        }
    } else {
        // ---- degcnt path: ONE u64 atomic/edge: [63:40]=count, [39:0]=deg fx ----
        int e = (blockIdx.x - NB) * 256 + threadIdx.x;
        if (e >= NE) return;
        int c = col[e];
        unsigned long long q = (unsigned long long)(unsigned)(w[e] * FIX + 0.5f);
        unsigned long long old = atomicAdd(&dc[c], (1ull << 40) | q);
        rank[e] = (unsigned short)(old >> 40);   // in-bucket rank (Poisson(16): <2^16)
    }
}

// -------- exclusive scan of counts -> offs (block-local) + bsum; deg -> dis.
// Consumers add bsum[i>>8] inline, so no scan3 fix-up kernel is needed.
__global__ __launch_bounds__(256) void k_scan1(const unsigned long long* __restrict__ dc,
                                               int* __restrict__ offs,
                                               int* __restrict__ bsum,
                                               float* __restrict__ dis) {
    __shared__ int s[256];
    int t = threadIdx.x, i = blockIdx.x * 256 + t;
    unsigned long long p = (i < NN) ? dc[i] : 0ull;
    int v = (int)(p >> 40);
    if (i < NN) {
        float d = (float)(p & ((1ull << 40) - 1)) * (1.0f / FIX);
        dis[i] = (d > 0.f) ? rsqrtf(d) : 0.f;
    }
    s[t] = v;
    __syncthreads();
    for (int off = 1; off < 256; off <<= 1) {
        int add = (t >= off) ? s[t - off] : 0;
        __syncthreads();
        s[t] += add;
        __syncthreads();
    }
    if (i < NN) offs[i] = s[t] - v;             // exclusive within block
    if (t == 255) bsum[blockIdx.x] = s[255];    // block total
}

__global__ __launch_bounds__(512) void k_scan2(int* __restrict__ bsum) {
    __shared__ int s[512];
    int t = threadIdx.x;
    int v = (t < NB) ? bsum[t] : 0;
    s[t] = v;
    __syncthreads();
    for (int off = 1; off < 512; off <<= 1) {
        int add = (t >= off) ? s[t - off] : 0;
        __syncthreads();
        s[t] += add;
        __syncthreads();
    }
    if (t < NB) bsum[t] = s[t] - v;             // exclusive block offsets
}

// CSR scatter, atomic-free: slot = offs[c] + bsum[c>>8] + rank[e].
// Fused {row, norm} int2 store: one scattered cacheline per edge.
__global__ __launch_bounds__(256) void k_scatter(const int* __restrict__ row,
                                                 const int* __restrict__ col,
                                                 const float* __restrict__ w,
                                                 const float* __restrict__ dis,
                                                 const int* __restrict__ offs,
                                                 const int* __restrict__ bsum,
                                                 const unsigned short* __restrict__ rank,
                                                 int2* __restrict__ pair) {
    int e = blockIdx.x * 256 + threadIdx.x;
    if (e >= NE) return;
    int r = row[e], c = col[e];
    int p = offs[c] + bsum[c >> 8] + rank[e];
    int2 pr;
    pr.x = r;
    pr.y = __float_as_int(dis[r] * w[e] * dis[c]);
    pair[p] = pr;
}

// Pull-based hop: 2 threads per node, 20 floats (5 float4) each.
// VMEM per edge: 2 pair(b64) + 10 gather(b128) = 12, vs 20 for the old
// 10-thread mapping — hops are VMEM-issue-bound (VALUBusy ~1%, HBM ~15%).
__global__ __launch_bounds__(256) void k_hop_pull(const int* __restrict__ offs,
                                                  const int* __restrict__ bsum,
                                                  const int2* __restrict__ pair,
                                                  const float* __restrict__ hin,
                                                  float* __restrict__ hout) {
    int tid = blockIdx.x * 256 + threadIdx.x;
    if (tid >= NN * 2) return;
    int n = tid >> 1;
    int vo = (tid & 1) * 20;          // float offset 0 or 20
    int s0 = offs[n] + bsum[n >> 8];
    int np = n + 1;
    int s1 = (np == NN) ? NE : (offs[np] + bsum[np >> 8]);
    float acc[20];
#pragma unroll
    for (int j = 0; j < 20; ++j) acc[j] = 0.f;
    int i = s0;
    for (; i + 2 <= s1; i += 2) {
        int2 p0 = pair[i];
        int2 p1 = pair[i + 1];
        const float* b0 = hin + (size_t)p0.x * NC + vo;
        const float* b1 = hin + (size_t)p1.x * NC + vo;
        float w0 = __int_as_float(p0.y);
        float w1 = __int_as_float(p1.y);
#pragma unroll
        for (int j = 0; j < 5; ++j) {
            float4 m0 = *(const float4*)(b0 + j * 4);
            acc[j * 4 + 0] += m0.x * w0;
            acc[j * 4 + 1] += m0.y * w0;
            acc[j * 4 + 2] += m0.z * w0;
            acc[j * 4 + 3] += m0.w * w0;
        }
#pragma unroll
        for (int j = 0; j < 5; ++j) {
            float4 m1 = *(const float4*)(b1 + j * 4);
            acc[j * 4 + 0] += m1.x * w1;
            acc[j * 4 + 1] += m1.y * w1;
            acc[j * 4 + 2] += m1.z * w1;
            acc[j * 4 + 3] += m1.w * w1;
        }
    }
    if (i < s1) {
        int2 p0 = pair[i];
        const float* b0 = hin + (size_t)p0.x * NC + vo;
        float w0 = __int_as_float(p0.y);
#pragma unroll
        for (int j = 0; j < 5; ++j) {
            float4 m0 = *(const float4*)(b0 + j * 4);
            acc[j * 4 + 0] += m0.x * w0;
            acc[j * 4 + 1] += m0.y * w0;
            acc[j * 4 + 2] += m0.z * w0;
            acc[j * 4 + 3] += m0.w * w0;
        }
    }
    float* o = hout + (size_t)n * NC + vo;
#pragma unroll
    for (int j = 0; j < 5; ++j) {
        float4 v = {acc[j * 4 + 0], acc[j * 4 + 1], acc[j * 4 + 2], acc[j * 4 + 3]};
        *(float4*)(o + j * 4) = v;
    }
}

extern "C" void kernel_launch(void* const* d_in, const int* in_sizes, int n_in,
                              void* d_out, int out_size, void* d_ws, size_t ws_size,
                              hipStream_t stream) {
    const float* x  = (const float*)d_in[0];
    const int*   ei = (const int*)d_in[1];   // [2, NE]
    const float* w  = (const float*)d_in[2];
    const float* W  = (const float*)d_in[3]; // [128, 40]
    const int* row = ei;
    const int* col = ei + NE;
    float* out = (float*)d_out;              // [NN, NC] — ping-pong partner of ha

    // workspace carve-up (16B-aligned): ~33.6 MB total
    char* p = (char*)d_ws;
    unsigned long long* dc = (unsigned long long*)p; p += (size_t)NN * 8;   // packed cnt|deg
    float* dis  = (float*)p; p += (size_t)NN * 4;
    int*   offs = (int*)p;   p += (size_t)(NN + 4) * 4;
    int*   bsum = (int*)p;   p += 512 * 4;
    int2*  pair = (int2*)p;  p += (size_t)NE * 8;         // CSR {row, norm}
    unsigned short* rank = (unsigned short*)p; p += (size_t)NE * 2;
    float* ha   = (float*)p;                              // [NN, NC] h0 / h2

    hipMemsetAsync(dc, 0, (size_t)NN * 8, stream);
    k_build<<<NB + EB, 256, 0, stream>>>(col, w, x, W, dc, rank, ha);  // xw ∥ degcnt
    k_scan1<<<NB, 256, 0, stream>>>(dc, offs, bsum, dis);
    k_scan2<<<1, 512, 0, stream>>>(bsum);
    k_scatter<<<EB, 256, 0, stream>>>(row, col, w, dis, offs, bsum, rank, pair);

    const int hopBlocks = (NN * 2 + 255) / 256;
    k_hop_pull<<<hopBlocks, 256, 0, stream>>>(offs, bsum, pair, ha, out);   // hop 1
    k_hop_pull<<<hopBlocks, 256, 0, stream>>>(offs, bsum, pair, out, ha);   // hop 2
    k_hop_pull<<<hopBlocks, 256, 0, stream>>>(offs, bsum, pair, ha, out);   // hop 3
}

// Round 6
// 413.963 us; speedup vs baseline: 1.1322x; 1.1322x over previous
//
#include <hip/hip_runtime.h>

namespace {
constexpr int NN = 100000;   // nodes
constexpr int NE = 1600000;  // edges
constexpr int NF = 128;      // input feats
constexpr int NC = 40;       // classes (propagated dim after algebraic reorder)
constexpr int NB = (NN + 255) / 256;  // node blocks = 391
constexpr int EB = (NE + 255) / 256;  // edge blocks = 6250
constexpr float FIX = 1048576.0f;     // 2^20 fixed-point scale for deg
}

// Fused kernel: blocks [0,NB) do H0 = x@W (VALU-heavy), blocks [NB,NB+EB) do
// the degree/count histogram (atomic-latency-bound). Disjoint inputs; the two
// populations co-schedule so xw hides inside degcnt's atomic latency.
// (256,2): min 2 waves/EU -> VGPR cap 256. R5's bare (256) made the backend
// pick a 24-VGPR budget and spill the xw acc[40] array to scratch.
__global__ __launch_bounds__(256, 2) void k_build(const int* __restrict__ col,
                                                  const float* __restrict__ w,
                                                  const float* __restrict__ x,
                                                  const float* __restrict__ W,
                                                  unsigned long long* __restrict__ dc,
                                                  unsigned short* __restrict__ rank,
                                                  float* __restrict__ h0) {
    if (blockIdx.x < (unsigned)NB) {
        // ---- xw path: thread per node, 40 accumulators, no LDS ----
        int n = blockIdx.x * 256 + threadIdx.x;
        if (n >= NN) return;
        const float4* xr = (const float4*)(x + (size_t)n * NF);  // 32 float4
        const float4* W4 = (const float4*)W;                     // row k = 10 float4
        float acc[NC];
#pragma unroll
        for (int j = 0; j < NC; ++j) acc[j] = 0.f;
        for (int k4 = 0; k4 < NF / 4; ++k4) {
            float4 xv = xr[k4];
#pragma unroll
            for (int kk = 0; kk < 4; ++kk) {
                float xk = (kk == 0) ? xv.x : (kk == 1) ? xv.y : (kk == 2) ? xv.z : xv.w;
                int k = k4 * 4 + kk;
#pragma unroll
                for (int j4 = 0; j4 < 10; ++j4) {
                    float4 wv = W4[k * 10 + j4];   // block-uniform address
                    acc[j4 * 4 + 0] += xk * wv.x;
                    acc[j4 * 4 + 1] += xk * wv.y;
                    acc[j4 * 4 + 2] += xk * wv.z;
                    acc[j4 * 4 + 3] += xk * wv.w;
                }
            }
        }
        float4* o = (float4*)(h0 + (size_t)n * NC);
#pragma unroll
        for (int j4 = 0; j4 < 10; ++j4) {
            float4 v = {acc[j4 * 4 + 0], acc[j4 * 4 + 1], acc[j4 * 4 + 2], acc[j4 * 4 + 3]};
            o[j4] = v;
        }
    } else {
        // ---- degcnt path: ONE u64 atomic/edge: [63:40]=count, [39:0]=deg fx ----
        int e = (blockIdx.x - NB) * 256 + threadIdx.x;
        if (e >= NE) return;
        int c = col[e];
        unsigned long long q = (unsigned long long)(unsigned)(w[e] * FIX + 0.5f);
        unsigned long long old = atomicAdd(&dc[c], (1ull << 40) | q);
        rank[e] = (unsigned short)(old >> 40);   // in-bucket rank (Poisson(16): <2^16)
    }
}

// -------- exclusive scan of counts -> offs (block-local) + bsum; deg -> dis.
// Consumers add bsum[i>>8] inline (no scan3 fix-up kernel).
__global__ __launch_bounds__(256) void k_scan1(const unsigned long long* __restrict__ dc,
                                               int* __restrict__ offs,
                                               int* __restrict__ bsum,
                                               float* __restrict__ dis) {
    __shared__ int s[256];
    int t = threadIdx.x, i = blockIdx.x * 256 + t;
    unsigned long long p = (i < NN) ? dc[i] : 0ull;
    int v = (int)(p >> 40);
    if (i < NN) {
        float d = (float)(p & ((1ull << 40) - 1)) * (1.0f / FIX);
        dis[i] = (d > 0.f) ? rsqrtf(d) : 0.f;
    }
    s[t] = v;
    __syncthreads();
    for (int off = 1; off < 256; off <<= 1) {
        int add = (t >= off) ? s[t - off] : 0;
        __syncthreads();
        s[t] += add;
        __syncthreads();
    }
    if (i < NN) offs[i] = s[t] - v;             // exclusive within block
    if (t == 255) bsum[blockIdx.x] = s[255];    // block total
}

__global__ __launch_bounds__(512) void k_scan2(int* __restrict__ bsum) {
    __shared__ int s[512];
    int t = threadIdx.x;
    int v = (t < NB) ? bsum[t] : 0;
    s[t] = v;
    __syncthreads();
    for (int off = 1; off < 512; off <<= 1) {
        int add = (t >= off) ? s[t - off] : 0;
        __syncthreads();
        s[t] += add;
        __syncthreads();
    }
    if (t < NB) bsum[t] = s[t] - v;             // exclusive block offsets
}

// CSR scatter, atomic-free: slot = offs[c] + bsum[c>>8] + rank[e].
// Fused {row, norm} int2 store: one scattered cacheline per edge.
__global__ __launch_bounds__(256) void k_scatter(const int* __restrict__ row,
                                                 const int* __restrict__ col,
                                                 const float* __restrict__ w,
                                                 const float* __restrict__ dis,
                                                 const int* __restrict__ offs,
                                                 const int* __restrict__ bsum,
                                                 const unsigned short* __restrict__ rank,
                                                 int2* __restrict__ pair) {
    int e = blockIdx.x * 256 + threadIdx.x;
    if (e >= NE) return;
    int r = row[e], c = col[e];
    int p = offs[c] + bsum[c >> 8] + rank[e];
    int2 pr;
    pr.x = r;
    pr.y = __float_as_int(dis[r] * w[e] * dis[c]);
    pair[p] = pr;
}

// Pull-based hop: 5 threads per node, 8 floats (2 float4) each.
// VMEM/edge = 5 pair + 10 gather = 15 (R4's 10-thr map: 20 -> 65 µs at
// 1.25 cyc/issue; R5's 2-thr map: 12 but latency/divergence-bound -> ~100).
// 500k threads keeps occupancy + short per-lane gather chains.
__global__ __launch_bounds__(256) void k_hop_pull(const int* __restrict__ offs,
                                                  const int* __restrict__ bsum,
                                                  const int2* __restrict__ pair,
                                                  const float* __restrict__ hin,
                                                  float* __restrict__ hout) {
    int tid = blockIdx.x * 256 + threadIdx.x;
    if (tid >= NN * 5) return;
    int n = tid / 5;
    int vo = (tid - n * 5) * 8;       // float offset 0,8,16,24,32
    int s0 = offs[n] + bsum[n >> 8];
    int np = n + 1;
    int s1 = (np == NN) ? NE : (offs[np] + bsum[np >> 8]);
    float acc[8];
#pragma unroll
    for (int j = 0; j < 8; ++j) acc[j] = 0.f;
    int i = s0;
    for (; i + 2 <= s1; i += 2) {
        int2 p0 = pair[i];
        int2 p1 = pair[i + 1];
        const float* b0 = hin + (size_t)p0.x * NC + vo;
        const float* b1 = hin + (size_t)p1.x * NC + vo;
        float4 m00 = *(const float4*)(b0);
        float4 m01 = *(const float4*)(b0 + 4);
        float4 m10 = *(const float4*)(b1);
        float4 m11 = *(const float4*)(b1 + 4);
        float w0 = __int_as_float(p0.y);
        float w1 = __int_as_float(p1.y);
        acc[0] += m00.x * w0; acc[1] += m00.y * w0;
        acc[2] += m00.z * w0; acc[3] += m00.w * w0;
        acc[4] += m01.x * w0; acc[5] += m01.y * w0;
        acc[6] += m01.z * w0; acc[7] += m01.w * w0;
        acc[0] += m10.x * w1; acc[1] += m10.y * w1;
        acc[2] += m10.z * w1; acc[3] += m10.w * w1;
        acc[4] += m11.x * w1; acc[5] += m11.y * w1;
        acc[6] += m11.z * w1; acc[7] += m11.w * w1;
    }
    if (i < s1) {
        int2 p0 = pair[i];
        const float* b0 = hin + (size_t)p0.x * NC + vo;
        float4 m00 = *(const float4*)(b0);
        float4 m01 = *(const float4*)(b0 + 4);
        float w0 = __int_as_float(p0.y);
        acc[0] += m00.x * w0; acc[1] += m00.y * w0;
        acc[2] += m00.z * w0; acc[3] += m00.w * w0;
        acc[4] += m01.x * w0; acc[5] += m01.y * w0;
        acc[6] += m01.z * w0; acc[7] += m01.w * w0;
    }
    float* o = hout + (size_t)n * NC + vo;
    float4 v0 = {acc[0], acc[1], acc[2], acc[3]};
    float4 v1 = {acc[4], acc[5], acc[6], acc[7]};
    *(float4*)(o) = v0;
    *(float4*)(o + 4) = v1;
}

extern "C" void kernel_launch(void* const* d_in, const int* in_sizes, int n_in,
                              void* d_out, int out_size, void* d_ws, size_t ws_size,
                              hipStream_t stream) {
    const float* x  = (const float*)d_in[0];
    const int*   ei = (const int*)d_in[1];   // [2, NE]
    const float* w  = (const float*)d_in[2];
    const float* W  = (const float*)d_in[3]; // [128, 40]
    const int* row = ei;
    const int* col = ei + NE;
    float* out = (float*)d_out;              // [NN, NC] — ping-pong partner of ha

    // workspace carve-up (16B-aligned)
    char* p = (char*)d_ws;
    unsigned long long* dc = (unsigned long long*)p; p += (size_t)NN * 8;   // packed cnt|deg
    float* dis  = (float*)p; p += (size_t)NN * 4;
    int*   offs = (int*)p;   p += (size_t)(NN + 4) * 4;
    int*   bsum = (int*)p;   p += 512 * 4;
    int2*  pair = (int2*)p;  p += (size_t)NE * 8;         // CSR {row, norm}
    unsigned short* rank = (unsigned short*)p; p += (size_t)NE * 2;
    float* ha   = (float*)p;                              // [NN, NC] h0 / h2

    hipMemsetAsync(dc, 0, (size_t)NN * 8, stream);
    k_build<<<NB + EB, 256, 0, stream>>>(col, w, x, W, dc, rank, ha);  // xw ∥ degcnt
    k_scan1<<<NB, 256, 0, stream>>>(dc, offs, bsum, dis);
    k_scan2<<<1, 512, 0, stream>>>(bsum);
    k_scatter<<<EB, 256, 0, stream>>>(row, col, w, dis, offs, bsum, rank, pair);

    const int hopBlocks = (NN * 5 + 255) / 256;
    k_hop_pull<<<hopBlocks, 256, 0, stream>>>(offs, bsum, pair, ha, out);   // hop 1
    k_hop_pull<<<hopBlocks, 256, 0, stream>>>(offs, bsum, pair, out, ha);   // hop 2
    k_hop_pull<<<hopBlocks, 256, 0, stream>>>(offs, bsum, pair, ha, out);   // hop 3
}

// Round 7
// 348.766 us; speedup vs baseline: 1.3438x; 1.1869x over previous
//
#include <hip/hip_runtime.h>
#include <hip/hip_fp16.h>

namespace {
constexpr int NN = 100000;   // nodes
constexpr int NE = 1600000;  // edges
constexpr int NF = 128;      // input feats
constexpr int NC = 40;       // classes (propagated dim after algebraic reorder)
constexpr int HP = 64;       // padded h row: 64 halfs = 128 B = exactly 1 L2 line
constexpr int NB = (NN + 255) / 256;  // node blocks = 391
constexpr int EB = (NE + 255) / 256;  // edge blocks = 6250
constexpr float FIX = 1048576.0f;     // 2^20 fixed-point scale for deg
}

struct alignas(16) H8 { __half2 a, b, c, d; };   // 8 halfs = one b128

__device__ inline __half2 f2h2(float x, float y) {
    return __halves2half2(__float2half_rn(x), __float2half_rn(y));
}

// Fused: blocks [0,NB) compute H0 = x@W -> fp16 padded rows; blocks [NB,..)
// do the degree/count histogram (ONE u64 atomic/edge: [63:40]=cnt, [39:0]=deg
// fixed-point; returned cnt field = edge's rank within its col bucket).
__global__ __launch_bounds__(256, 2) void k_build(const int* __restrict__ col,
                                                  const float* __restrict__ w,
                                                  const float* __restrict__ x,
                                                  const float* __restrict__ W,
                                                  unsigned long long* __restrict__ dc,
                                                  unsigned char* __restrict__ rank,
                                                  __half* __restrict__ h0) {
    if (blockIdx.x < (unsigned)NB) {
        int n = blockIdx.x * 256 + threadIdx.x;
        if (n >= NN) return;
        const float4* xr = (const float4*)(x + (size_t)n * NF);  // 32 float4
        const float4* W4 = (const float4*)W;                     // row k = 10 float4
        float acc[NC];
#pragma unroll
        for (int j = 0; j < NC; ++j) acc[j] = 0.f;
        for (int k4 = 0; k4 < NF / 4; ++k4) {
            float4 xv = xr[k4];
#pragma unroll
            for (int kk = 0; kk < 4; ++kk) {
                float xk = (kk == 0) ? xv.x : (kk == 1) ? xv.y : (kk == 2) ? xv.z : xv.w;
                int k = k4 * 4 + kk;
#pragma unroll
                for (int j4 = 0; j4 < 10; ++j4) {
                    float4 wv = W4[k * 10 + j4];   // wave-uniform address
                    acc[j4 * 4 + 0] += xk * wv.x;
                    acc[j4 * 4 + 1] += xk * wv.y;
                    acc[j4 * 4 + 2] += xk * wv.z;
                    acc[j4 * 4 + 3] += xk * wv.w;
                }
            }
        }
        H8* o = (H8*)(h0 + (size_t)n * HP);
#pragma unroll
        for (int g = 0; g < 5; ++g) {   // 5 x 8 halfs = 40
            H8 v;
            v.a = f2h2(acc[g * 8 + 0], acc[g * 8 + 1]);
            v.b = f2h2(acc[g * 8 + 2], acc[g * 8 + 3]);
            v.c = f2h2(acc[g * 8 + 4], acc[g * 8 + 5]);
            v.d = f2h2(acc[g * 8 + 6], acc[g * 8 + 7]);
            o[g] = v;
        }
    } else {
        int e = (blockIdx.x - NB) * 256 + threadIdx.x;
        if (e >= NE) return;
        int c = col[e];
        unsigned long long q = (unsigned long long)(unsigned)(w[e] * FIX + 0.5f);
        unsigned long long old = atomicAdd(&dc[c], (1ull << 40) | q);
        rank[e] = (unsigned char)(old >> 40);   // max in-degree ~42 (Poisson 16)
    }
}

// exclusive scan of counts -> offs (block-local) + bsum; deg -> dis.
// Consumers add bsum[i>>8] inline (no fix-up kernel).
__global__ __launch_bounds__(256) void k_scan1(const unsigned long long* __restrict__ dc,
                                               int* __restrict__ offs,
                                               int* __restrict__ bsum,
                                               float* __restrict__ dis) {
    __shared__ int s[256];
    int t = threadIdx.x, i = blockIdx.x * 256 + t;
    unsigned long long p = (i < NN) ? dc[i] : 0ull;
    int v = (int)(p >> 40);
    if (i < NN) {
        float d = (float)(p & ((1ull << 40) - 1)) * (1.0f / FIX);
        dis[i] = (d > 0.f) ? rsqrtf(d) : 0.f;
    }
    s[t] = v;
    __syncthreads();
    for (int off = 1; off < 256; off <<= 1) {
        int add = (t >= off) ? s[t - off] : 0;
        __syncthreads();
        s[t] += add;
        __syncthreads();
    }
    if (i < NN) offs[i] = s[t] - v;
    if (t == 255) bsum[blockIdx.x] = s[255];
}

__global__ __launch_bounds__(512) void k_scan2(int* __restrict__ bsum) {
    __shared__ int s[512];
    int t = threadIdx.x;
    int v = (t < NB) ? bsum[t] : 0;
    s[t] = v;
    __syncthreads();
    for (int off = 1; off < 512; off <<= 1) {
        int add = (t >= off) ? s[t - off] : 0;
        __syncthreads();
        s[t] += add;
        __syncthreads();
    }
    if (t < NB) bsum[t] = s[t] - v;
}

// CSR scatter, atomic-free: slot = offs[c] + bsum[c>>8] + rank[e].
// Fused {row, norm} int2 store: one scattered cacheline per edge.
__global__ __launch_bounds__(256) void k_scatter(const int* __restrict__ row,
                                                 const int* __restrict__ col,
                                                 const float* __restrict__ w,
                                                 const float* __restrict__ dis,
                                                 const int* __restrict__ offs,
                                                 const int* __restrict__ bsum,
                                                 const unsigned char* __restrict__ rank,
                                                 int2* __restrict__ pair) {
    int e = blockIdx.x * 256 + threadIdx.x;
    if (e >= NE) return;
    int r = row[e], c = col[e];
    int p = offs[c] + bsum[c >> 8] + rank[e];
    int2 pr;
    pr.x = r;
    pr.y = __float_as_int(dis[r] * w[e] * dis[c]);
    pair[p] = pr;
}

// Pull hop, fp16 -> fp16. 5 threads/node x 8 halfs: ONE b128 gather per
// (edge, thread); each padded row is exactly one 128 B line -> per-edge
// cache traffic 128 B (fp32-unpadded was 256 B; hops were L2/L3-BW-bound).
__global__ __launch_bounds__(256) void k_hop_hh(const int* __restrict__ offs,
                                                const int* __restrict__ bsum,
                                                const int2* __restrict__ pair,
                                                const __half* __restrict__ hin,
                                                __half* __restrict__ hout) {
    int tid = blockIdx.x * 256 + threadIdx.x;
    if (tid >= NN * 5) return;
    int n = tid / 5;
    int vo = (tid - n * 5) * 8;       // half offset 0,8,16,24,32
    int s0 = offs[n] + bsum[n >> 8];
    int np = n + 1;
    int s1 = (np == NN) ? NE : (offs[np] + bsum[np >> 8]);
    float acc[8];
#pragma unroll
    for (int j = 0; j < 8; ++j) acc[j] = 0.f;
    int i = s0;
    for (; i + 2 <= s1; i += 2) {
        int2 p0 = pair[i];
        int2 p1 = pair[i + 1];
        H8 m0 = *(const H8*)(hin + (size_t)p0.x * HP + vo);
        H8 m1 = *(const H8*)(hin + (size_t)p1.x * HP + vo);
        float w0 = __int_as_float(p0.y);
        float w1 = __int_as_float(p1.y);
        float2 f;
        f = __half22float2(m0.a); acc[0] += f.x * w0; acc[1] += f.y * w0;
        f = __half22float2(m0.b); acc[2] += f.x * w0; acc[3] += f.y * w0;
        f = __half22float2(m0.c); acc[4] += f.x * w0; acc[5] += f.y * w0;
        f = __half22float2(m0.d); acc[6] += f.x * w0; acc[7] += f.y * w0;
        f = __half22float2(m1.a); acc[0] += f.x * w1; acc[1] += f.y * w1;
        f = __half22float2(m1.b); acc[2] += f.x * w1; acc[3] += f.y * w1;
        f = __half22float2(m1.c); acc[4] += f.x * w1; acc[5] += f.y * w1;
        f = __half22float2(m1.d); acc[6] += f.x * w1; acc[7] += f.y * w1;
    }
    if (i < s1) {
        int2 p0 = pair[i];
        H8 m0 = *(const H8*)(hin + (size_t)p0.x * HP + vo);
        float w0 = __int_as_float(p0.y);
        float2 f;
        f = __half22float2(m0.a); acc[0] += f.x * w0; acc[1] += f.y * w0;
        f = __half22float2(m0.b); acc[2] += f.x * w0; acc[3] += f.y * w0;
        f = __half22float2(m0.c); acc[4] += f.x * w0; acc[5] += f.y * w0;
        f = __half22float2(m0.d); acc[6] += f.x * w0; acc[7] += f.y * w0;
    }
    H8 v;
    v.a = f2h2(acc[0], acc[1]);
    v.b = f2h2(acc[2], acc[3]);
    v.c = f2h2(acc[4], acc[5]);
    v.d = f2h2(acc[6], acc[7]);
    *(H8*)(hout + (size_t)n * HP + vo) = v;
}

// Final hop: fp16 gather -> fp32 d_out (unpadded 40-float rows).
__global__ __launch_bounds__(256) void k_hop_hf(const int* __restrict__ offs,
                                                const int* __restrict__ bsum,
                                                const int2* __restrict__ pair,
                                                const __half* __restrict__ hin,
                                                float* __restrict__ out) {
    int tid = blockIdx.x * 256 + threadIdx.x;
    if (tid >= NN * 5) return;
    int n = tid / 5;
    int vo = (tid - n * 5) * 8;
    int s0 = offs[n] + bsum[n >> 8];
    int np = n + 1;
    int s1 = (np == NN) ? NE : (offs[np] + bsum[np >> 8]);
    float acc[8];
#pragma unroll
    for (int j = 0; j < 8; ++j) acc[j] = 0.f;
    int i = s0;
    for (; i + 2 <= s1; i += 2) {
        int2 p0 = pair[i];
        int2 p1 = pair[i + 1];
        H8 m0 = *(const H8*)(hin + (size_t)p0.x * HP + vo);
        H8 m1 = *(const H8*)(hin + (size_t)p1.x * HP + vo);
        float w0 = __int_as_float(p0.y);
        float w1 = __int_as_float(p1.y);
        float2 f;
        f = __half22float2(m0.a); acc[0] += f.x * w0; acc[1] += f.y * w0;
        f = __half22float2(m0.b); acc[2] += f.x * w0; acc[3] += f.y * w0;
        f = __half22float2(m0.c); acc[4] += f.x * w0; acc[5] += f.y * w0;
        f = __half22float2(m0.d); acc[6] += f.x * w0; acc[7] += f.y * w0;
        f = __half22float2(m1.a); acc[0] += f.x * w1; acc[1] += f.y * w1;
        f = __half22float2(m1.b); acc[2] += f.x * w1; acc[3] += f.y * w1;
        f = __half22float2(m1.c); acc[4] += f.x * w1; acc[5] += f.y * w1;
        f = __half22float2(m1.d); acc[6] += f.x * w1; acc[7] += f.y * w1;
    }
    if (i < s1) {
        int2 p0 = pair[i];
        H8 m0 = *(const H8*)(hin + (size_t)p0.x * HP + vo);
        float w0 = __int_as_float(p0.y);
        float2 f;
        f = __half22float2(m0.a); acc[0] += f.x * w0; acc[1] += f.y * w0;
        f = __half22float2(m0.b); acc[2] += f.x * w0; acc[3] += f.y * w0;
        f = __half22float2(m0.c); acc[4] += f.x * w0; acc[5] += f.y * w0;
        f = __half22float2(m0.d); acc[6] += f.x * w0; acc[7] += f.y * w0;
    }
    float* o = out + (size_t)n * NC + vo;
    float4 v0 = {acc[0], acc[1], acc[2], acc[3]};
    float4 v1 = {acc[4], acc[5], acc[6], acc[7]};
    *(float4*)(o) = v0;
    *(float4*)(o + 4) = v1;
}

extern "C" void kernel_launch(void* const* d_in, const int* in_sizes, int n_in,
                              void* d_out, int out_size, void* d_ws, size_t ws_size,
                              hipStream_t stream) {
    const float* x  = (const float*)d_in[0];
    const int*   ei = (const int*)d_in[1];   // [2, NE]
    const float* w  = (const float*)d_in[2];
    const float* W  = (const float*)d_in[3]; // [128, 40]
    const int* row = ei;
    const int* col = ei + NE;
    float* out = (float*)d_out;              // [NN, NC] fp32, written by hop3 only

    // workspace (~38.8 MB): hb OVERLAYS {dc, dis, rank} — all dead once
    // k_scatter finishes, and hb is first written by hop1 (after scatter).
    char* base = (char*)d_ws;
    __half* hb = (__half*)base;                               // [NN, HP] fp16
    unsigned long long* dc = (unsigned long long*)base;       //   [0, 0.8 MB)
    float* dis = (float*)(base + (size_t)NN * 8);             //   [0.8, 1.2)
    unsigned char* rank = (unsigned char*)(base + (size_t)NN * 12);  // [1.2, 2.8)
    char* p = base + (size_t)NN * HP * 2;                     // end of hb region
    int*  offs = (int*)p;   p += (size_t)(NN + 4) * 4;
    int*  bsum = (int*)p;   p += 512 * 4;
    int2* pair = (int2*)p;  p += (size_t)NE * 8;              // CSR {row, norm}
    __half* ha = (__half*)p;                                  // [NN, HP] fp16

    hipMemsetAsync(dc, 0, (size_t)NN * 8, stream);
    k_build<<<NB + EB, 256, 0, stream>>>(col, w, x, W, dc, rank, ha);  // xw ∥ degcnt
    k_scan1<<<NB, 256, 0, stream>>>(dc, offs, bsum, dis);
    k_scan2<<<1, 512, 0, stream>>>(bsum);
    k_scatter<<<EB, 256, 0, stream>>>(row, col, w, dis, offs, bsum, rank, pair);

    const int hopBlocks = (NN * 5 + 255) / 256;
    k_hop_hh<<<hopBlocks, 256, 0, stream>>>(offs, bsum, pair, ha, hb);   // hop 1
    k_hop_hh<<<hopBlocks, 256, 0, stream>>>(offs, bsum, pair, hb, ha);   // hop 2
    k_hop_hf<<<hopBlocks, 256, 0, stream>>>(offs, bsum, pair, ha, out);  // hop 3
}

// Round 8
// 328.822 us; speedup vs baseline: 1.4253x; 1.0607x over previous
//
#include <hip/hip_runtime.h>
#include <hip/hip_fp16.h>

namespace {
constexpr int NN = 100000;   // nodes
constexpr int NE = 1600000;  // edges
constexpr int NF = 128;      // input feats
constexpr int NC = 40;       // classes (propagated dim after algebraic reorder)
constexpr int HP = 64;       // padded h row: 64 halfs = 128 B = exactly 1 L2 line
constexpr int NB = (NN + 255) / 256;  // node blocks = 391
constexpr int EB = (NE + 255) / 256;  // edge blocks = 6250
constexpr float FIX = 1048576.0f;     // 2^20 fixed-point scale for deg
constexpr int NPB = 51;               // nodes per hop block (51*5 = 255 threads)
constexpr int HB  = (NN + NPB - 1) / NPB;  // hop blocks = 1961
constexpr int TS  = 2048;             // staged pairs per tile (16 KB LDS)
}

struct alignas(16) H8 { __half2 a, b, c, d; };   // 8 halfs = one b128

__device__ inline __half2 f2h2(float x, float y) {
    return __halves2half2(__float2half_rn(x), __float2half_rn(y));
}

// Fused: blocks [0,NB) compute H0 = x@W -> fp16 padded rows; blocks [NB,..)
// do the degree/count histogram (ONE u64 atomic/edge: [63:40]=cnt, [39:0]=deg
// fixed-point; returned cnt field = edge's rank within its col bucket).
__global__ __launch_bounds__(256, 2) void k_build(const int* __restrict__ col,
                                                  const float* __restrict__ w,
                                                  const float* __restrict__ x,
                                                  const float* __restrict__ W,
                                                  unsigned long long* __restrict__ dc,
                                                  unsigned char* __restrict__ rank,
                                                  __half* __restrict__ h0) {
    if (blockIdx.x < (unsigned)NB) {
        int n = blockIdx.x * 256 + threadIdx.x;
        if (n >= NN) return;
        const float4* xr = (const float4*)(x + (size_t)n * NF);  // 32 float4
        const float4* W4 = (const float4*)W;                     // row k = 10 float4
        float acc[NC];
#pragma unroll
        for (int j = 0; j < NC; ++j) acc[j] = 0.f;
        for (int k4 = 0; k4 < NF / 4; ++k4) {
            float4 xv = xr[k4];
#pragma unroll
            for (int kk = 0; kk < 4; ++kk) {
                float xk = (kk == 0) ? xv.x : (kk == 1) ? xv.y : (kk == 2) ? xv.z : xv.w;
                int k = k4 * 4 + kk;
#pragma unroll
                for (int j4 = 0; j4 < 10; ++j4) {
                    float4 wv = W4[k * 10 + j4];   // wave-uniform address
                    acc[j4 * 4 + 0] += xk * wv.x;
                    acc[j4 * 4 + 1] += xk * wv.y;
                    acc[j4 * 4 + 2] += xk * wv.z;
                    acc[j4 * 4 + 3] += xk * wv.w;
                }
            }
        }
        H8* o = (H8*)(h0 + (size_t)n * HP);
#pragma unroll
        for (int g = 0; g < 5; ++g) {   // 5 x 8 halfs = 40
            H8 v;
            v.a = f2h2(acc[g * 8 + 0], acc[g * 8 + 1]);
            v.b = f2h2(acc[g * 8 + 2], acc[g * 8 + 3]);
            v.c = f2h2(acc[g * 8 + 4], acc[g * 8 + 5]);
            v.d = f2h2(acc[g * 8 + 6], acc[g * 8 + 7]);
            o[g] = v;
        }
    } else {
        int e = (blockIdx.x - NB) * 256 + threadIdx.x;
        if (e >= NE) return;
        int c = col[e];
        unsigned long long q = (unsigned long long)(unsigned)(w[e] * FIX + 0.5f);
        unsigned long long old = atomicAdd(&dc[c], (1ull << 40) | q);
        rank[e] = (unsigned char)(old >> 40);   // max in-degree ~42 (Poisson 16)
    }
}

// exclusive scan of counts -> offs (block-local) + bsum; deg -> dis.
// Consumers add bsum[i>>8] inline (no fix-up kernel).
__global__ __launch_bounds__(256) void k_scan1(const unsigned long long* __restrict__ dc,
                                               int* __restrict__ offs,
                                               int* __restrict__ bsum,
                                               float* __restrict__ dis) {
    __shared__ int s[256];
    int t = threadIdx.x, i = blockIdx.x * 256 + t;
    unsigned long long p = (i < NN) ? dc[i] : 0ull;
    int v = (int)(p >> 40);
    if (i < NN) {
        float d = (float)(p & ((1ull << 40) - 1)) * (1.0f / FIX);
        dis[i] = (d > 0.f) ? rsqrtf(d) : 0.f;
    }
    s[t] = v;
    __syncthreads();
    for (int off = 1; off < 256; off <<= 1) {
        int add = (t >= off) ? s[t - off] : 0;
        __syncthreads();
        s[t] += add;
        __syncthreads();
    }
    if (i < NN) offs[i] = s[t] - v;
    if (t == 255) bsum[blockIdx.x] = s[255];
}

__global__ __launch_bounds__(512) void k_scan2(int* __restrict__ bsum) {
    __shared__ int s[512];
    int t = threadIdx.x;
    int v = (t < NB) ? bsum[t] : 0;
    s[t] = v;
    __syncthreads();
    for (int off = 1; off < 512; off <<= 1) {
        int add = (t >= off) ? s[t - off] : 0;
        __syncthreads();
        s[t] += add;
        __syncthreads();
    }
    if (t < NB) bsum[t] = s[t] - v;
}

// CSR scatter, atomic-free: slot = offs[c] + bsum[c>>8] + rank[e].
// Fused {row, norm} stored as one 8 B NONTEMPORAL store (nt bit skips the
// write-allocate RFO on 1.6M scattered lines).
__global__ __launch_bounds__(256) void k_scatter(const int* __restrict__ row,
                                                 const int* __restrict__ col,
                                                 const float* __restrict__ w,
                                                 const float* __restrict__ dis,
                                                 const int* __restrict__ offs,
                                                 const int* __restrict__ bsum,
                                                 const unsigned char* __restrict__ rank,
                                                 int2* __restrict__ pair) {
    int e = blockIdx.x * 256 + threadIdx.x;
    if (e >= NE) return;
    int r = row[e], c = col[e];
    int p = offs[c] + bsum[c >> 8] + rank[e];
    unsigned long long v = (unsigned long long)(unsigned)r |
        ((unsigned long long)(unsigned)__float_as_int(dis[r] * w[e] * dis[c]) << 32);
    __builtin_nontemporal_store(v, (unsigned long long*)(pair + p));
}

// LDS-staged pull hop. Block = 51 nodes x 5 threads (255 active). The block's
// CSR segment [E0,E1) is contiguous -> stage pairs into LDS cooperatively
// (1 coalesced b64 VMEM per edge), then the 5 threads/node read pairs from
// LDS (broadcast, conflict-free). VMEM/edge: 1 stage + 5 gathers = 6
// (was 10: 5 redundant pair loads + 5 gathers -> hops were VMEM-issue-bound).
template <bool FINAL>
__global__ __launch_bounds__(256) void k_hop(const int* __restrict__ offs,
                                             const int* __restrict__ bsum,
                                             const int2* __restrict__ pair,
                                             const __half* __restrict__ hin,
                                             __half* __restrict__ houth,
                                             float* __restrict__ houtf) {
    __shared__ int2 tile[TS];
    __shared__ int erange[2];
    int t = threadIdx.x;
    int g = t / 5;                      // local node 0..50
    int n = blockIdx.x * NPB + g;
    bool active = (t < NPB * 5) && (n < NN);
    int vo = (t - g * 5) * 8;           // half offset 0,8,16,24,32
    int s0 = 0, s1 = 0;
    if (active) {
        s0 = offs[n] + bsum[n >> 8];
        int np = n + 1;
        s1 = (np == NN) ? NE : (offs[np] + bsum[np >> 8]);
    }
    if (t == 0) {
        int n0 = blockIdx.x * NPB;
        erange[0] = offs[n0] + bsum[n0 >> 8];
        int nl = n0 + NPB;
        erange[1] = (nl >= NN) ? NE : (offs[nl] + bsum[nl >> 8]);
    }
    __syncthreads();
    int E0 = erange[0], E1 = erange[1];
    float acc[8];
#pragma unroll
    for (int j = 0; j < 8; ++j) acc[j] = 0.f;
    int i = s0;
    for (int t0 = E0; t0 < E1; t0 += TS) {
        int lim = min(t0 + TS, E1);
        int cnt = lim - t0;
        for (int j = t; j < cnt; j += 256) tile[j] = pair[t0 + j];  // coalesced
        __syncthreads();
        if (active) {
            int hi = min(s1, lim);
            for (; i + 2 <= hi; i += 2) {
                int2 p0 = tile[i - t0];
                int2 p1 = tile[i + 1 - t0];
                H8 m0 = *(const H8*)(hin + (size_t)p0.x * HP + vo);
                H8 m1 = *(const H8*)(hin + (size_t)p1.x * HP + vo);
                float w0 = __int_as_float(p0.y);
                float w1 = __int_as_float(p1.y);
                float2 f;
                f = __half22float2(m0.a); acc[0] += f.x * w0; acc[1] += f.y * w0;
                f = __half22float2(m0.b); acc[2] += f.x * w0; acc[3] += f.y * w0;
                f = __half22float2(m0.c); acc[4] += f.x * w0; acc[5] += f.y * w0;
                f = __half22float2(m0.d); acc[6] += f.x * w0; acc[7] += f.y * w0;
                f = __half22float2(m1.a); acc[0] += f.x * w1; acc[1] += f.y * w1;
                f = __half22float2(m1.b); acc[2] += f.x * w1; acc[3] += f.y * w1;
                f = __half22float2(m1.c); acc[4] += f.x * w1; acc[5] += f.y * w1;
                f = __half22float2(m1.d); acc[6] += f.x * w1; acc[7] += f.y * w1;
            }
            if (i < hi) {
                int2 p0 = tile[i - t0];
                H8 m0 = *(const H8*)(hin + (size_t)p0.x * HP + vo);
                float w0 = __int_as_float(p0.y);
                float2 f;
                f = __half22float2(m0.a); acc[0] += f.x * w0; acc[1] += f.y * w0;
                f = __half22float2(m0.b); acc[2] += f.x * w0; acc[3] += f.y * w0;
                f = __half22float2(m0.c); acc[4] += f.x * w0; acc[5] += f.y * w0;
                f = __half22float2(m0.d); acc[6] += f.x * w0; acc[7] += f.y * w0;
                ++i;
            }
        }
        __syncthreads();
    }
    if (active) {
        if (FINAL) {
            float* o = houtf + (size_t)n * NC + vo;
            float4 v0 = {acc[0], acc[1], acc[2], acc[3]};
            float4 v1 = {acc[4], acc[5], acc[6], acc[7]};
            *(float4*)(o) = v0;
            *(float4*)(o + 4) = v1;
        } else {
            H8 v;
            v.a = f2h2(acc[0], acc[1]);
            v.b = f2h2(acc[2], acc[3]);
            v.c = f2h2(acc[4], acc[5]);
            v.d = f2h2(acc[6], acc[7]);
            *(H8*)(houth + (size_t)n * HP + vo) = v;
        }
    }
}

extern "C" void kernel_launch(void* const* d_in, const int* in_sizes, int n_in,
                              void* d_out, int out_size, void* d_ws, size_t ws_size,
                              hipStream_t stream) {
    const float* x  = (const float*)d_in[0];
    const int*   ei = (const int*)d_in[1];   // [2, NE]
    const float* w  = (const float*)d_in[2];
    const float* W  = (const float*)d_in[3]; // [128, 40]
    const int* row = ei;
    const int* col = ei + NE;
    float* out = (float*)d_out;              // [NN, NC] fp32, written by hop3 only

    // workspace (~38.8 MB): hb OVERLAYS {dc, dis, rank} — all dead once
    // k_scatter finishes; hb is first written by hop1 (after scatter).
    char* base = (char*)d_ws;
    __half* hb = (__half*)base;                               // [NN, HP] fp16
    unsigned long long* dc = (unsigned long long*)base;       //   [0, 0.8 MB)
    float* dis = (float*)(base + (size_t)NN * 8);             //   [0.8, 1.2)
    unsigned char* rank = (unsigned char*)(base + (size_t)NN * 12);  // [1.2, 2.8)
    char* p = base + (size_t)NN * HP * 2;                     // end of hb region
    int*  offs = (int*)p;   p += (size_t)(NN + 4) * 4;
    int*  bsum = (int*)p;   p += 512 * 4;
    int2* pair = (int2*)p;  p += (size_t)NE * 8;              // CSR {row, norm}
    __half* ha = (__half*)p;                                  // [NN, HP] fp16

    hipMemsetAsync(dc, 0, (size_t)NN * 8, stream);
    k_build<<<NB + EB, 256, 0, stream>>>(col, w, x, W, dc, rank, ha);  // xw ∥ degcnt
    k_scan1<<<NB, 256, 0, stream>>>(dc, offs, bsum, dis);
    k_scan2<<<1, 512, 0, stream>>>(bsum);
    k_scatter<<<EB, 256, 0, stream>>>(row, col, w, dis, offs, bsum, rank, pair);

    k_hop<false><<<HB, 256, 0, stream>>>(offs, bsum, pair, ha, hb, nullptr);  // hop 1
    k_hop<false><<<HB, 256, 0, stream>>>(offs, bsum, pair, hb, ha, nullptr);  // hop 2
    k_hop<true ><<<HB, 256, 0, stream>>>(offs, bsum, pair, ha, nullptr, out); // hop 3
}